// Round 8
// baseline (231.945 us; speedup 1.0000x reference)
//
#include <hip/hip_runtime.h>
#include <stdint.h>

#define S_LEN 2048
#define DIM   2048
#define NHEAD 32
#define KVHEAD 8
#define HDIM  64
#define NQKV  3072

typedef __attribute__((ext_vector_type(8))) __bf16 bf16x8;
typedef __attribute__((ext_vector_type(4))) float f32x4;
typedef __attribute__((ext_vector_type(8))) unsigned short u16x8;
typedef __attribute__((ext_vector_type(4))) unsigned int u32x4;

#if __has_builtin(__builtin_amdgcn_exp2f)
#define EXP2F(x) __builtin_amdgcn_exp2f(x)
#else
#define EXP2F(x) exp2f(x)
#endif

__device__ __forceinline__ unsigned short f2bf(float f) {
  unsigned u = __builtin_bit_cast(unsigned, f);
  unsigned r = (u + 0x7FFFu + ((u >> 16) & 1u)) >> 16;   // RNE
  return (unsigned short)r;
}
__device__ __forceinline__ float bf2f(unsigned short h) {
  unsigned u = ((unsigned)h) << 16;
  return __builtin_bit_cast(float, u);
}

// async global->LDS, 16B per lane. LDS dest = wave-uniform base (+ lane*16 by HW).
__device__ __forceinline__ void gl_lds16(const void* g, void* l) {
  __builtin_amdgcn_global_load_lds(
      (const __attribute__((address_space(1))) unsigned*)g,
      (__attribute__((address_space(3))) unsigned*)l, 16, 0, 0);
}

// ---------------- fused prep: weight transposes + x convert + bias concat ----
__global__ void prep_kernel(const float* __restrict__ x,
                            const float* __restrict__ bq,
                            const float* __restrict__ bk,
                            const float* __restrict__ bv,
                            const float* __restrict__ Wq,
                            const float* __restrict__ Wk,
                            const float* __restrict__ Wv,
                            const float* __restrict__ Wo,
                            unsigned short* __restrict__ xb,
                            unsigned short* __restrict__ WqkvT,
                            unsigned short* __restrict__ WoT,
                            float* __restrict__ bqkv) {
  int idx = blockIdx.x;
  int tid = threadIdx.x;
  if (idx < 10240) {
    __shared__ float t[32][33];
    int bx = idx >> 6, by = idx & 63;
    const float* src; int C, sc, dbase; unsigned short* dst;
    if (bx < 64)      { src = Wq; C = 2048; sc = bx * 32;        dst = WqkvT; dbase = sc; }
    else if (bx < 80) { src = Wk; C = 512;  sc = (bx - 64) * 32; dst = WqkvT; dbase = 2048 + sc; }
    else if (bx < 96) { src = Wv; C = 512;  sc = (bx - 80) * 32; dst = WqkvT; dbase = 2560 + sc; }
    else              { src = Wo; C = 2048; sc = (bx - 96) * 32; dst = WoT;   dbase = sc; }
    int tx = tid & 31, ty = tid >> 5;
#pragma unroll
    for (int j = 0; j < 32; j += 8)
      t[ty + j][tx] = src[(size_t)(by * 32 + ty + j) * C + sc + tx];
    __syncthreads();
#pragma unroll
    for (int j = 0; j < 32; j += 8)
      dst[(size_t)(dbase + ty + j) * 2048 + by * 32 + tx] = f2bf(t[tx][ty + j]);
  } else if (idx < 14336) {
    int i = (idx - 10240) * 256 + tid;         // < 1048576 exactly
    float4 v = ((const float4*)x)[i];
    ushort4 o;
    o.x = f2bf(v.x); o.y = f2bf(v.y); o.z = f2bf(v.z); o.w = f2bf(v.w);
    ((ushort4*)xb)[i] = o;
  } else {
    int i = (idx - 14336) * 256 + tid;
    if (i < NQKV)
      bqkv[i] = (i < 2048) ? bq[i] : (i < 2560 ? bk[i - 2048] : bv[i - 2560]);
  }
}

// ---------------- fused RoPE (q,k in qkv) + V transpose (VT) ----------------
__global__ void rope_vt_kernel(unsigned short* __restrict__ qkv,
                               const float* __restrict__ fc,
                               const float* __restrict__ fs,
                               unsigned short* __restrict__ VT) {
  int idx = blockIdx.x;
  int tid = threadIdx.x;
  if (idx < 10240) {
    int i = idx * 256 + tid;                 // pair index, < 2621440 exactly
    int row = i / 1280;
    int p   = i - row * 1280;
    int col = (p < 1024) ? (p * 2) : (2048 + (p - 1024) * 2);
    int fi = p & 31;
    float c  = fc[row * 32 + fi];
    float sn = fs[row * 32 + fi];
    unsigned* base = (unsigned*)(qkv + (size_t)row * NQKV + col);
    unsigned v = *base;
    float x0 = bf2f((unsigned short)(v & 0xFFFF));
    float x1 = bf2f((unsigned short)(v >> 16));
    unsigned short o0 = f2bf(x0 * c - x1 * sn);
    unsigned short o1 = f2bf(x0 * sn + x1 * c);
    *base = (unsigned)o0 | ((unsigned)o1 << 16);
  } else {
    __shared__ unsigned short t[32][33];
    int sub = idx - 10240;
    int bx = (sub & 15) * 32;   // C
    int by = (sub >> 4) * 32;   // R
    int tx = tid & 31, ty = tid >> 5;
    const unsigned short* src = qkv + 2560;
#pragma unroll
    for (int j = 0; j < 32; j += 8)
      t[ty + j][tx] = src[(size_t)(by + ty + j) * 3072 + bx + tx];
    __syncthreads();
#pragma unroll
    for (int j = 0; j < 32; j += 8)
      VT[(size_t)(bx + ty + j) * 2048 + by + tx] = t[tx][ty + j];
  }
}

// ---------------- GEMM: C[M][N] = A[M][K] * BT[N][K]^T + bias ----------------
// 128x64 tile, BK=64, 8 waves = 4 spatial (2x2) x 2 K-halves (in-block split-K).
// 3-buffer counted-vmcnt pipeline (T4): loads never drained to 0 mid-loop.
template <int OUT_BF16>
__global__ __launch_bounds__(512, 4) void gemm_bt_kernel(
    const unsigned short* __restrict__ A,
    const unsigned short* __restrict__ BT,
    const float* __restrict__ bias,
    void* __restrict__ Cc, int M, int N, int K) {
  constexpr int BUFB = 16384 + 8192;       // A tile + B tile bytes
  __shared__ char smem[3 * BUFB];          // 72 KB
  const int tid = threadIdx.x;
  const int lane = tid & 63;
  const int wid = tid >> 6;
  const int kh = wid >> 2;           // K-half
  const int wsub = wid & 3;
  const int wm = wsub >> 1, wn = wsub & 1;
  const int rowA0 = blockIdx.x * 128;
  const int rowB0 = blockIdx.y * 64;
  const int l15 = lane & 15, l4 = lane >> 4;
  const int kcol = kh * 64 + l4 * 16;

  f32x4 acc[4][2];
#pragma unroll
  for (int i = 0; i < 4; i++)
#pragma unroll
    for (int j = 0; j < 2; j++) acc[i][j] = (f32x4){0.f, 0.f, 0.f, 0.f};

  const int nK = K >> 6;

  auto stage = [&](int buf, int kt) {
    const char* Ab = (const char*)A + ((size_t)rowA0 * K + (size_t)kt * 64) * 2;
    const char* Bb = (const char*)BT + ((size_t)rowB0 * K + (size_t)kt * 64) * 2;
    char* Sb = smem + buf * BUFB;
    // A tile: 2 x 8KB halves (3 gl_lds per thread total per stage)
#pragma unroll
    for (int h = 0; h < 2; ++h) {
      int o = h * 8192 + tid * 16;
      int r = o >> 7;
      int cb = (o & 127) ^ ((r & 7) << 4);
      gl_lds16(Ab + (size_t)r * (K * 2) + cb, Sb + o);
    }
    {
      int o = tid * 16;
      int r = o >> 7;
      int cb = (o & 127) ^ ((r & 7) << 4);
      gl_lds16(Bb + (size_t)r * (K * 2) + cb, Sb + 16384 + o);
    }
  };

  stage(0, 0);
  if (nK > 1) stage(1, 1);

  for (int kt = 0; kt < nK; ++kt) {
    if (kt + 1 < nK) { asm volatile("s_waitcnt vmcnt(3)" ::: "memory"); }
    else             { asm volatile("s_waitcnt vmcnt(0)" ::: "memory"); }
    __builtin_amdgcn_s_barrier();
    asm volatile("" ::: "memory");
    if (kt + 2 < nK) stage((kt + 2) % 3, kt + 2);
    char* Sb = smem + (kt % 3) * BUFB;

    bf16x8 af[4], bfr[2];
#pragma unroll
    for (int i = 0; i < 4; i++) {
      int ra = wm * 64 + i * 16 + l15;
      af[i] = *(const bf16x8*)(Sb + ra * 128 + (kcol ^ ((ra & 7) << 4)));
    }
#pragma unroll
    for (int j = 0; j < 2; j++) {
      int rb = wn * 32 + j * 16 + l15;
      bfr[j] = *(const bf16x8*)(Sb + 16384 + rb * 128 + (kcol ^ ((rb & 7) << 4)));
    }
#pragma unroll
    for (int i = 0; i < 4; i++)
#pragma unroll
      for (int j = 0; j < 2; j++)
        acc[i][j] = __builtin_amdgcn_mfma_f32_16x16x32_bf16(af[i], bfr[j], acc[i][j], 0, 0, 0);
  }

  // combine K-halves through LDS, then kh==0 waves write C
  __syncthreads();
  f32x4* eps = (f32x4*)smem;
  if (kh == 1) {
#pragma unroll
    for (int i = 0; i < 4; i++)
#pragma unroll
      for (int j = 0; j < 2; j++)
        eps[wsub * 512 + (i * 2 + j) * 64 + lane] = acc[i][j];
  }
  __syncthreads();
  if (kh == 0) {
#pragma unroll
    for (int i = 0; i < 4; i++) {
      int row0 = rowA0 + wm * 64 + i * 16 + l4 * 4;
#pragma unroll
      for (int j = 0; j < 2; j++) {
        f32x4 oth = eps[wsub * 512 + (i * 2 + j) * 64 + lane];
        int col = rowB0 + wn * 32 + j * 16 + l15;
        float bv_ = bias[col];
#pragma unroll
        for (int r = 0; r < 4; r++) {
          float v = acc[i][j][r] + oth[r] + bv_;
          size_t idx = (size_t)(row0 + r) * N + col;
          if (OUT_BF16) ((unsigned short*)Cc)[idx] = f2bf(v);
          else          ((float*)Cc)[idx] = v;
        }
      }
    }
  }
}

// ---------------- causal GQA flash attention ----------------
// 512 blocks: qt = 63 - (bid>>3) (heavy-first), kvh = bid&7.
// block = 4 waves x 256 thr; wave = 1 head x 32 q-rows (2 q-groups of 16).
// Each K/V fragment read from LDS feeds BOTH q-groups -> block LDS traffic halved.
// 3-buffer counted-vmcnt pipeline; swapped QK^T (T12): P stays in registers,
// PV A-fragments via v_cvt_pk_bf16_f32 + permlane32/16_swap. setprio on MFMA (T5).
__global__ __launch_bounds__(256, 2) void attn_kernel(
    const unsigned short* __restrict__ qkv,
    const unsigned short* __restrict__ VT,   // [512][2048] = [kvh*64+d][s]
    unsigned short* __restrict__ O) {
  __shared__ unsigned short Ks[3][64 * 64];    // [kv][d], 128B rows, swizzled
  __shared__ unsigned short VTs[3][64 * 64];   // [d][kv], 128B rows, swizzled

  const int tid = threadIdx.x;                 // 0..255
  const int lane = tid & 63;
  const int w = tid >> 6;                      // head within group
  const int l15 = lane & 15, l4 = lane >> 4;
  const int kvh = blockIdx.x & 7;
  const int qt  = 63 - (blockIdx.x >> 3);      // heavy blocks dispatched first
  const int h = kvh * 4 + w;
  const int nt = (qt >> 1) + 1;
  const int qbase = qt * 32;

  auto issue = [&](int buf, int t) {
    int kvb = t * 64;
#pragma unroll
    for (int hf = 0; hf < 2; ++hf) {
      int o = hf * 4096 + tid * 16;
      int r = o >> 7;
      int cb = (o & 127) ^ ((r & 7) << 4);
      gl_lds16((const char*)qkv + ((size_t)(kvb + r) * NQKV + 2048 + kvh * 64) * 2 + cb,
               (char*)&Ks[buf][0] + o);
      gl_lds16((const char*)VT + ((size_t)(kvh * 64 + r) * S_LEN + kvb) * 2 + cb,
               (char*)&VTs[buf][0] + o);
    }
  };

  // Q fragments for both q-groups, pre-scaled by (1/8)*log2(e) -> bare v_exp
  bf16x8 qf[2][2];
#pragma unroll
  for (int qg = 0; qg < 2; ++qg) {
    const unsigned short* qrow = qkv + (size_t)(qbase + qg * 16 + l15) * NQKV + h * 64;
#pragma unroll
    for (int kf = 0; kf < 2; ++kf) {
      u16x8 raw = *(const u16x8*)(qrow + kf * 32 + l4 * 8);
      u16x8 sc;
#pragma unroll
      for (int i = 0; i < 8; i++) sc[i] = f2bf(bf2f(raw[i]) * 0.1803368801111f);
      qf[qg][kf] = __builtin_bit_cast(bf16x8, sc);
    }
  }

  f32x4 oacc[2][4];
  float lsum[2] = {0.f, 0.f};
#pragma unroll
  for (int qg = 0; qg < 2; ++qg)
#pragma unroll
    for (int d = 0; d < 4; d++) oacc[qg][d] = (f32x4){0.f, 0.f, 0.f, 0.f};

  issue(0, 0);
  if (nt > 1) issue(1, 1);

  for (int t = 0; t < nt; ++t) {
    if (t + 1 < nt) { asm volatile("s_waitcnt vmcnt(4)" ::: "memory"); }
    else            { asm volatile("s_waitcnt vmcnt(0)" ::: "memory"); }
    __builtin_amdgcn_s_barrier();
    asm volatile("" ::: "memory");
    if (t + 2 < nt) issue((t + 2) % 3, t + 2);
    const int buf = t % 3;

    // S^T = K Q^T: lane holds S[q = l15 (+qg*16)][k = nf*16 + l4*4 + r]
    f32x4 sacc[2][4];
#pragma unroll
    for (int qg = 0; qg < 2; ++qg)
#pragma unroll
      for (int nf = 0; nf < 4; nf++) sacc[qg][nf] = (f32x4){0.f, 0.f, 0.f, 0.f};
    __builtin_amdgcn_s_setprio(1);
#pragma unroll
    for (int nf = 0; nf < 4; nf++) {
#pragma unroll
      for (int kf = 0; kf < 2; kf++) {
        int row = nf * 16 + l15;
        bf16x8 kb = *(const bf16x8*)((const char*)&Ks[buf][0] + row * 128 +
                                     ((kf * 64 + l4 * 16) ^ ((row & 7) << 4)));
        sacc[0][nf] = __builtin_amdgcn_mfma_f32_16x16x32_bf16(kb, qf[0][kf], sacc[0][nf], 0, 0, 0);
        sacc[1][nf] = __builtin_amdgcn_mfma_f32_16x16x32_bf16(kb, qf[1][kf], sacc[1][nf], 0, 0, 0);
      }
    }
    __builtin_amdgcn_s_setprio(0);

    // causal mask (last tile only)
    if (t == nt - 1) {
      int kvb = t * 64;
#pragma unroll
      for (int qg = 0; qg < 2; ++qg) {
        int qpos = qbase + qg * 16 + l15;
#pragma unroll
        for (int nf = 0; nf < 4; nf++) {
#pragma unroll
          for (int r = 0; r < 4; r++) {
            int kvpos = kvb + nf * 16 + l4 * 4 + r;
            if (kvpos > qpos) sacc[qg][nf][r] = -3.0e38f;
          }
        }
      }
    }

    // p = exp2(s'); per-lane row-sum partial (lane owns 16 k's per q-group)
#pragma unroll
    for (int qg = 0; qg < 2; ++qg)
#pragma unroll
      for (int nf = 0; nf < 4; nf++)
#pragma unroll
        for (int r = 0; r < 4; r++) {
          float p = EXP2F(sacc[qg][nf][r]);
          lsum[qg] += p;
          sacc[qg][nf][r] = p;
        }

    // pack P to bf16 + permlane redistribution -> PV A-fragments (per q-group)
    bf16x8 paf[2][2];
#pragma unroll
    for (int qg = 0; qg < 2; ++qg) {
      unsigned wds[4][2];
#pragma unroll
      for (int nf = 0; nf < 4; nf++)
#pragma unroll
        for (int m = 0; m < 2; m++)
          asm("v_cvt_pk_bf16_f32 %0, %1, %2"
              : "=v"(wds[nf][m]) : "v"(sacc[qg][nf][2 * m]), "v"(sacc[qg][nf][2 * m + 1]));
#pragma unroll
      for (int kc = 0; kc < 2; kc++) {
        unsigned a0 = wds[2 * kc][0], b0 = wds[2 * kc + 1][0];
        unsigned a1 = wds[2 * kc][1], b1 = wds[2 * kc + 1][1];
        asm("v_permlane32_swap_b32 %0, %1" : "+v"(a0), "+v"(b0));
        asm("v_permlane16_swap_b32 %0, %1" : "+v"(a0), "+v"(b0));
        asm("v_permlane32_swap_b32 %0, %1" : "+v"(a1), "+v"(b1));
        asm("v_permlane16_swap_b32 %0, %1" : "+v"(a1), "+v"(b1));
        u32x4 afu = (u32x4){a0, a1, b0, b1};
        paf[qg][kc] = __builtin_bit_cast(bf16x8, afu);
      }
    }

    // O += P V  (each V fragment feeds both q-groups)
    __builtin_amdgcn_s_setprio(1);
#pragma unroll
    for (int kc = 0; kc < 2; kc++) {
#pragma unroll
      for (int df = 0; df < 4; df++) {
        int row = df * 16 + l15;
        bf16x8 vb = *(const bf16x8*)((const char*)&VTs[buf][0] + row * 128 +
                                     ((kc * 64 + l4 * 16) ^ ((row & 7) << 4)));
        oacc[0][df] = __builtin_amdgcn_mfma_f32_16x16x32_bf16(paf[0][kc], vb, oacc[0][df], 0, 0, 0);
        oacc[1][df] = __builtin_amdgcn_mfma_f32_16x16x32_bf16(paf[1][kc], vb, oacc[1][df], 0, 0, 0);
      }
    }
    __builtin_amdgcn_s_setprio(0);
  }

  // finish row-sums + store
#pragma unroll
  for (int qg = 0; qg < 2; ++qg) {
    lsum[qg] += __shfl_xor(lsum[qg], 16, 64);
    lsum[qg] += __shfl_xor(lsum[qg], 32, 64);
#pragma unroll
    for (int r = 0; r < 4; r++) {
      float inv = 1.0f / __shfl(lsum[qg], l4 * 4 + r, 16);
      int qpos = qbase + qg * 16 + l4 * 4 + r;
#pragma unroll
      for (int df = 0; df < 4; df++)
        O[(size_t)qpos * DIM + h * 64 + df * 16 + l15] = f2bf(oacc[qg][df][r] * inv);
    }
  }
}

// ---------------- host launcher ----------------
extern "C" void kernel_launch(void* const* d_in, const int* in_sizes, int n_in,
                              void* d_out, int out_size, void* d_ws, size_t ws_size,
                              hipStream_t stream) {
  const float* x  = (const float*)d_in[0];
  const float* fc = (const float*)d_in[1];
  const float* fs = (const float*)d_in[2];
  // d_in[3] = mask (causality implemented directly)
  const float* Wq = (const float*)d_in[4];
  const float* bq = (const float*)d_in[5];
  const float* Wk = (const float*)d_in[6];
  const float* bk = (const float*)d_in[7];
  const float* Wv = (const float*)d_in[8];
  const float* bv = (const float*)d_in[9];
  const float* Wo = (const float*)d_in[10];
  const float* bo = (const float*)d_in[11];
  float* out = (float*)d_out;

  char* ws = (char*)d_ws;
  unsigned short* xb    = (unsigned short*)(ws + 0);          // 8 MB (reused as attn out)
  unsigned short* WqkvT = (unsigned short*)(ws + 8388608);    // 12 MB (reused as VT)
  unsigned short* WoT   = (unsigned short*)(ws + 20971520);   // 8 MB
  float*          bqkv  = (float*)(ws + 29360128);            // 12 KB
  unsigned short* qkv   = (unsigned short*)(ws + 29372416);   // 12 MB
  unsigned short* VT    = WqkvT;                              // alias (after gemm1)
  unsigned short* attn  = xb;                                 // alias (after gemm1)

  prep_kernel<<<14348, 256, 0, stream>>>(x, bq, bk, bv, Wq, Wk, Wv, Wo,
                                         xb, WqkvT, WoT, bqkv);
  gemm_bt_kernel<1><<<dim3(16, 48), 512, 0, stream>>>(xb, WqkvT, bqkv, qkv, 2048, 3072, 2048);
  rope_vt_kernel<<<11264, 256, 0, stream>>>(qkv, fc, fs, VT);
  attn_kernel<<<512, 256, 0, stream>>>(qkv, VT, attn);
  gemm_bt_kernel<0><<<dim3(16, 32), 512, 0, stream>>>(attn, WoT, bo, out, 2048, 2048, 2048);
}

// Round 9
// 215.081 us; speedup vs baseline: 1.0784x; 1.0784x over previous
//
#include <hip/hip_runtime.h>
#include <stdint.h>

#define S_LEN 2048
#define DIM   2048
#define NHEAD 32
#define KVHEAD 8
#define HDIM  64
#define NQKV  3072

typedef __attribute__((ext_vector_type(8))) __bf16 bf16x8;
typedef __attribute__((ext_vector_type(4))) float f32x4;
typedef __attribute__((ext_vector_type(8))) unsigned short u16x8;
typedef __attribute__((ext_vector_type(4))) unsigned int u32x4;

#if __has_builtin(__builtin_amdgcn_exp2f)
#define EXP2F(x) __builtin_amdgcn_exp2f(x)
#else
#define EXP2F(x) exp2f(x)
#endif

__device__ __forceinline__ unsigned short f2bf(float f) {
  unsigned u = __builtin_bit_cast(unsigned, f);
  unsigned r = (u + 0x7FFFu + ((u >> 16) & 1u)) >> 16;   // RNE
  return (unsigned short)r;
}
__device__ __forceinline__ float bf2f(unsigned short h) {
  unsigned u = ((unsigned)h) << 16;
  return __builtin_bit_cast(float, u);
}

// async global->LDS, 16B per lane. LDS dest = wave-uniform base (+ lane*16 by HW).
__device__ __forceinline__ void gl_lds16(const void* g, void* l) {
  __builtin_amdgcn_global_load_lds(
      (const __attribute__((address_space(1))) unsigned*)g,
      (__attribute__((address_space(3))) unsigned*)l, 16, 0, 0);
}

// ---------------- fused prep: weight transposes + x convert + bias concat ----
__global__ void prep_kernel(const float* __restrict__ x,
                            const float* __restrict__ bq,
                            const float* __restrict__ bk,
                            const float* __restrict__ bv,
                            const float* __restrict__ Wq,
                            const float* __restrict__ Wk,
                            const float* __restrict__ Wv,
                            const float* __restrict__ Wo,
                            unsigned short* __restrict__ xb,
                            unsigned short* __restrict__ WqkvT,
                            unsigned short* __restrict__ WoT,
                            float* __restrict__ bqkv) {
  int idx = blockIdx.x;
  int tid = threadIdx.x;
  if (idx < 10240) {
    __shared__ float t[32][33];
    int bx = idx >> 6, by = idx & 63;
    const float* src; int C, sc, dbase; unsigned short* dst;
    if (bx < 64)      { src = Wq; C = 2048; sc = bx * 32;        dst = WqkvT; dbase = sc; }
    else if (bx < 80) { src = Wk; C = 512;  sc = (bx - 64) * 32; dst = WqkvT; dbase = 2048 + sc; }
    else if (bx < 96) { src = Wv; C = 512;  sc = (bx - 80) * 32; dst = WqkvT; dbase = 2560 + sc; }
    else              { src = Wo; C = 2048; sc = (bx - 96) * 32; dst = WoT;   dbase = sc; }
    int tx = tid & 31, ty = tid >> 5;
#pragma unroll
    for (int j = 0; j < 32; j += 8)
      t[ty + j][tx] = src[(size_t)(by * 32 + ty + j) * C + sc + tx];
    __syncthreads();
#pragma unroll
    for (int j = 0; j < 32; j += 8)
      dst[(size_t)(dbase + ty + j) * 2048 + by * 32 + tx] = f2bf(t[tx][ty + j]);
  } else if (idx < 14336) {
    int i = (idx - 10240) * 256 + tid;         // < 1048576 exactly
    float4 v = ((const float4*)x)[i];
    ushort4 o;
    o.x = f2bf(v.x); o.y = f2bf(v.y); o.z = f2bf(v.z); o.w = f2bf(v.w);
    ((ushort4*)xb)[i] = o;
  } else {
    int i = (idx - 14336) * 256 + tid;
    if (i < NQKV)
      bqkv[i] = (i < 2048) ? bq[i] : (i < 2560 ? bk[i - 2048] : bv[i - 2560]);
  }
}

// ---------------- fused RoPE (q,k in qkv) + V transpose (VT) ----------------
__global__ void rope_vt_kernel(unsigned short* __restrict__ qkv,
                               const float* __restrict__ fc,
                               const float* __restrict__ fs,
                               unsigned short* __restrict__ VT) {
  int idx = blockIdx.x;
  int tid = threadIdx.x;
  if (idx < 10240) {
    int i = idx * 256 + tid;                 // pair index, < 2621440 exactly
    int row = i / 1280;
    int p   = i - row * 1280;
    int col = (p < 1024) ? (p * 2) : (2048 + (p - 1024) * 2);
    int fi = p & 31;
    float c  = fc[row * 32 + fi];
    float sn = fs[row * 32 + fi];
    unsigned* base = (unsigned*)(qkv + (size_t)row * NQKV + col);
    unsigned v = *base;
    float x0 = bf2f((unsigned short)(v & 0xFFFF));
    float x1 = bf2f((unsigned short)(v >> 16));
    unsigned short o0 = f2bf(x0 * c - x1 * sn);
    unsigned short o1 = f2bf(x0 * sn + x1 * c);
    *base = (unsigned)o0 | ((unsigned)o1 << 16);
  } else {
    __shared__ unsigned short t[32][33];
    int sub = idx - 10240;
    int bx = (sub & 15) * 32;   // C
    int by = (sub >> 4) * 32;   // R
    int tx = tid & 31, ty = tid >> 5;
    const unsigned short* src = qkv + 2560;
#pragma unroll
    for (int j = 0; j < 32; j += 8)
      t[ty + j][tx] = src[(size_t)(by + ty + j) * 3072 + bx + tx];
    __syncthreads();
#pragma unroll
    for (int j = 0; j < 32; j += 8)
      VT[(size_t)(bx + ty + j) * 2048 + by + tx] = t[tx][ty + j];
  }
}

// ---------------- GEMM: C[M][N] = A[M][K] * BT[N][K]^T + bias ----------------
// 128 x (32*NJ) tile, BK=64, 8 waves = 4 spatial (2x2) x 2 K-halves (in-block split-K).
// 2-buf counted-vmcnt pipeline: stage(kt+1) -> vmcnt(3) -> barrier -> compute -> barrier.
template <int NJ, int OUT_BF16>
__global__ __launch_bounds__(512, 4) void gemm_bt_kernel(
    const unsigned short* __restrict__ A,
    const unsigned short* __restrict__ BT,
    const float* __restrict__ bias,
    void* __restrict__ Cc, int M, int N, int K) {
  constexpr int BUFB = 16384 + NJ * 4096;   // A tile + B tile bytes
  __shared__ char smem[2 * BUFB];
  const int tid = threadIdx.x;
  const int lane = tid & 63;
  const int wid = tid >> 6;
  const int kh = wid >> 2;           // K-half
  const int wsub = wid & 3;
  const int wm = wsub >> 1, wn = wsub & 1;
  const int rowA0 = blockIdx.x * 128;
  const int rowB0 = blockIdx.y * (32 * NJ);
  const int l15 = lane & 15, l4 = lane >> 4;
  const int kcol = kh * 64 + l4 * 16;

  f32x4 acc[4][NJ];
#pragma unroll
  for (int i = 0; i < 4; i++)
#pragma unroll
    for (int j = 0; j < NJ; j++) acc[i][j] = (f32x4){0.f, 0.f, 0.f, 0.f};

  const int nK = K >> 6;

  auto stage = [&](int buf, int kt) {
    const char* Ab = (const char*)A + ((size_t)rowA0 * K + (size_t)kt * 64) * 2;
    const char* Bb = (const char*)BT + ((size_t)rowB0 * K + (size_t)kt * 64) * 2;
    char* Sb = smem + buf * BUFB;
#pragma unroll
    for (int j = 0; j < 2; ++j) {
      int chunk = wid + 8 * j;
      int o = chunk * 1024 + lane * 16;
      int r = o >> 7;
      int cb = (o & 127) ^ ((r & 7) << 4);
      gl_lds16(Ab + (size_t)r * (K * 2) + cb, Sb + chunk * 1024);
    }
#pragma unroll
    for (int j = 0; j < (NJ + 1) / 2; ++j) {
      int chunk = wid + 8 * j;
      if (chunk < 4 * NJ) {
        int o = chunk * 1024 + lane * 16;
        int r = o >> 7;
        int cb = (o & 127) ^ ((r & 7) << 4);
        gl_lds16(Bb + (size_t)r * (K * 2) + cb, Sb + 16384 + chunk * 1024);
      }
    }
  };

  stage(0, 0);
  int buf = 0;

  for (int kt = 0; kt < nK; ++kt) {
    if (kt + 1 < nK) {
      stage(buf ^ 1, kt + 1);                       // prefetch stays in flight
      asm volatile("s_waitcnt vmcnt(3)" ::: "memory");
    } else {
      asm volatile("s_waitcnt vmcnt(0)" ::: "memory");
    }
    __builtin_amdgcn_s_barrier();
    asm volatile("" ::: "memory");

    bf16x8 af[4], bfr[NJ];
    char* Sb = smem + buf * BUFB;
#pragma unroll
    for (int i = 0; i < 4; i++) {
      int ra = wm * 64 + i * 16 + l15;
      af[i] = *(const bf16x8*)(Sb + ra * 128 + (kcol ^ ((ra & 7) << 4)));
    }
#pragma unroll
    for (int j = 0; j < NJ; j++) {
      int rb = wn * (NJ * 16) + j * 16 + l15;
      bfr[j] = *(const bf16x8*)(Sb + 16384 + rb * 128 + (kcol ^ ((rb & 7) << 4)));
    }
#pragma unroll
    for (int i = 0; i < 4; i++)
#pragma unroll
      for (int j = 0; j < NJ; j++)
        acc[i][j] = __builtin_amdgcn_mfma_f32_16x16x32_bf16(af[i], bfr[j], acc[i][j], 0, 0, 0);
    __builtin_amdgcn_s_barrier();
    asm volatile("" ::: "memory");
    buf ^= 1;
  }

  // combine K-halves through LDS, then kh==0 waves write C
  f32x4* eps = (f32x4*)smem;
  if (kh == 1) {
#pragma unroll
    for (int i = 0; i < 4; i++)
#pragma unroll
      for (int j = 0; j < NJ; j++)
        eps[wsub * (4 * NJ * 64) + (i * NJ + j) * 64 + lane] = acc[i][j];
  }
  __syncthreads();
  if (kh == 0) {
#pragma unroll
    for (int i = 0; i < 4; i++) {
      int row0 = rowA0 + wm * 64 + i * 16 + l4 * 4;
#pragma unroll
      for (int j = 0; j < NJ; j++) {
        f32x4 oth = eps[wsub * (4 * NJ * 64) + (i * NJ + j) * 64 + lane];
        int col = rowB0 + wn * (NJ * 16) + j * 16 + l15;
        float bv_ = bias[col];
#pragma unroll
        for (int r = 0; r < 4; r++) {
          float v = acc[i][j][r] + oth[r] + bv_;
          size_t idx = (size_t)(row0 + r) * N + col;
          if (OUT_BF16) ((unsigned short*)Cc)[idx] = f2bf(v);
          else          ((float*)Cc)[idx] = v;
        }
      }
    }
  }
}

// ---------------- causal GQA flash attention ----------------
// 512 blocks: qt = 63 - (bid>>3) (heavy-first), kvh = bid&7.
// 8 waves (head = w>>1, qsub=(w&1)*16), 16 q-rows/wave.
// 4-buffer LDS, 2-tile-per-iteration interleaved pipeline (two independent
// dependency chains per basic block), counted vmcnt (never 0 mid-loop).
// Swapped QK^T (T12): P in registers; PV A-frags via cvt_pk + permlane swaps.
__global__ __launch_bounds__(512, 4) void attn_kernel(
    const unsigned short* __restrict__ qkv,
    const unsigned short* __restrict__ VT,   // [512][2048] = [kvh*64+d][s]
    unsigned short* __restrict__ O) {
  __shared__ unsigned short Ks[4][64 * 64];    // [kv][d], 128B rows, swizzled
  __shared__ unsigned short VTs[4][64 * 64];   // [d][kv], 128B rows, swizzled

  const int tid = threadIdx.x;
  const int lane = tid & 63;
  const int w = tid >> 6;
  const int l15 = lane & 15, l4 = lane >> 4;
  const int kvh = blockIdx.x & 7;
  const int qt  = 63 - (blockIdx.x >> 3);      // heavy blocks dispatched first
  const int h = kvh * 4 + (w >> 1);
  const int qsub = (w & 1) * 16;
  const int nt = (qt >> 1) + 1;
  const int qbase = qt * 32;

  auto issue = [&](int buf, int t) {
    int kvb = t * 64;
    int o = tid << 4;
    int r = o >> 7;
    int cb = (o & 127) ^ ((r & 7) << 4);
    gl_lds16((const char*)qkv + ((size_t)(kvb + r) * NQKV + 2048 + kvh * 64) * 2 + cb,
             (char*)&Ks[buf][0] + o);
    gl_lds16((const char*)VT + ((size_t)(kvh * 64 + r) * S_LEN + kvb) * 2 + cb,
             (char*)&VTs[buf][0] + o);
  };

  // Q fragments, pre-scaled by (1/8)*log2(e): softmax is bare v_exp_f32 (exp2)
  bf16x8 qf[2];
  {
    const unsigned short* qrow = qkv + (size_t)(qbase + qsub + l15) * NQKV + h * 64;
#pragma unroll
    for (int kf = 0; kf < 2; ++kf) {
      u16x8 raw = *(const u16x8*)(qrow + kf * 32 + l4 * 8);
      u16x8 sc;
#pragma unroll
      for (int i = 0; i < 8; i++) sc[i] = f2bf(bf2f(raw[i]) * 0.1803368801111f);
      qf[kf] = __builtin_bit_cast(bf16x8, sc);
    }
  }

  f32x4 oacc[4];
  float lsum = 0.f;
#pragma unroll
  for (int d = 0; d < 4; d++) oacc[d] = (f32x4){0.f, 0.f, 0.f, 0.f};

  // one KV tile: QK^T -> (opt mask) -> exp2 -> pack/permute -> PV
  auto compute_tile = [&](int buf, int kvb, bool domask) {
    f32x4 sacc[4];
#pragma unroll
    for (int nf = 0; nf < 4; nf++) sacc[nf] = (f32x4){0.f, 0.f, 0.f, 0.f};
#pragma unroll
    for (int nf = 0; nf < 4; nf++) {
#pragma unroll
      for (int kf = 0; kf < 2; kf++) {
        int row = nf * 16 + l15;
        bf16x8 kb = *(const bf16x8*)((const char*)&Ks[buf][0] + row * 128 +
                                     ((kf * 64 + l4 * 16) ^ ((row & 7) << 4)));
        sacc[nf] = __builtin_amdgcn_mfma_f32_16x16x32_bf16(kb, qf[kf], sacc[nf], 0, 0, 0);
      }
    }
    if (domask) {
      int qpos = qbase + qsub + l15;
#pragma unroll
      for (int nf = 0; nf < 4; nf++) {
#pragma unroll
        for (int r = 0; r < 4; r++) {
          int kvpos = kvb + nf * 16 + l4 * 4 + r;
          if (kvpos > qpos) sacc[nf][r] = -3.0e38f;
        }
      }
    }
#pragma unroll
    for (int nf = 0; nf < 4; nf++)
#pragma unroll
      for (int r = 0; r < 4; r++) {
        float p = EXP2F(sacc[nf][r]);
        lsum += p;
        sacc[nf][r] = p;
      }
    unsigned wds[4][2];
#pragma unroll
    for (int nf = 0; nf < 4; nf++)
#pragma unroll
      for (int m = 0; m < 2; m++)
        asm("v_cvt_pk_bf16_f32 %0, %1, %2"
            : "=v"(wds[nf][m]) : "v"(sacc[nf][2 * m]), "v"(sacc[nf][2 * m + 1]));
    bf16x8 paf[2];
#pragma unroll
    for (int kc = 0; kc < 2; kc++) {
      unsigned a0 = wds[2 * kc][0], b0 = wds[2 * kc + 1][0];
      unsigned a1 = wds[2 * kc][1], b1 = wds[2 * kc + 1][1];
      asm("v_permlane32_swap_b32 %0, %1" : "+v"(a0), "+v"(b0));
      asm("v_permlane16_swap_b32 %0, %1" : "+v"(a0), "+v"(b0));
      asm("v_permlane32_swap_b32 %0, %1" : "+v"(a1), "+v"(b1));
      asm("v_permlane16_swap_b32 %0, %1" : "+v"(a1), "+v"(b1));
      u32x4 afu = (u32x4){a0, a1, b0, b1};
      paf[kc] = __builtin_bit_cast(bf16x8, afu);
    }
#pragma unroll
    for (int kc = 0; kc < 2; kc++) {
#pragma unroll
      for (int df = 0; df < 4; df++) {
        int row = df * 16 + l15;
        bf16x8 vb = *(const bf16x8*)((const char*)&VTs[buf][0] + row * 128 +
                                     ((kc * 64 + l4 * 16) ^ ((row & 7) << 4)));
        oacc[df] = __builtin_amdgcn_mfma_f32_16x16x32_bf16(paf[kc], vb, oacc[df], 0, 0, 0);
      }
    }
  };

  // prologue: up to 4 tiles in flight
  issue(0, 0);
  if (nt > 1) issue(1, 1);
  if (nt > 2) issue(2, 2);
  if (nt > 3) issue(3, 3);

  int t = 0;
  for (; t + 3 < nt; t += 2) {                      // pairs, never masked
    asm volatile("s_waitcnt vmcnt(4)" ::: "memory"); // t+2,t+3 stay in flight
    __builtin_amdgcn_s_barrier();
    asm volatile("" ::: "memory");
    __builtin_amdgcn_s_setprio(1);
    compute_tile(t & 3, t * 64, false);
    compute_tile((t + 1) & 3, (t + 1) * 64, false);
    __builtin_amdgcn_s_setprio(0);
    __builtin_amdgcn_s_barrier();
    asm volatile("" ::: "memory");
    if (t + 4 < nt) issue((t + 4) & 3, t + 4);
    if (t + 5 < nt) issue((t + 5) & 3, t + 5);
  }
  int rem = nt - t;
  if (rem == 3) {
    asm volatile("s_waitcnt vmcnt(2)" ::: "memory");
    __builtin_amdgcn_s_barrier();
    asm volatile("" ::: "memory");
    __builtin_amdgcn_s_setprio(1);
    compute_tile(t & 3, t * 64, false);
    compute_tile((t + 1) & 3, (t + 1) * 64, false);
    __builtin_amdgcn_s_setprio(0);
    asm volatile("s_waitcnt vmcnt(0)" ::: "memory");
    __builtin_amdgcn_s_barrier();
    asm volatile("" ::: "memory");
    compute_tile((t + 2) & 3, (t + 2) * 64, true);
  } else if (rem == 2) {
    asm volatile("s_waitcnt vmcnt(0)" ::: "memory");
    __builtin_amdgcn_s_barrier();
    asm volatile("" ::: "memory");
    __builtin_amdgcn_s_setprio(1);
    compute_tile(t & 3, t * 64, false);
    compute_tile((t + 1) & 3, (t + 1) * 64, true);
    __builtin_amdgcn_s_setprio(0);
  } else {
    asm volatile("s_waitcnt vmcnt(0)" ::: "memory");
    __builtin_amdgcn_s_barrier();
    asm volatile("" ::: "memory");
    compute_tile(t & 3, t * 64, true);
  }

  // finish row-sum: reduce across the 4 l4-groups (same l15 = same q-row)
  lsum += __shfl_xor(lsum, 16, 64);
  lsum += __shfl_xor(lsum, 32, 64);

  // epilogue: normalize + store bf16 (oacc row q = l4*4 + r; denom at lane l15 = q)
#pragma unroll
  for (int r = 0; r < 4; r++) {
    float inv = 1.0f / __shfl(lsum, l4 * 4 + r, 16);
    int qpos = qbase + qsub + l4 * 4 + r;
#pragma unroll
    for (int df = 0; df < 4; df++)
      O[(size_t)qpos * DIM + h * 64 + df * 16 + l15] = f2bf(oacc[df][r] * inv);
  }
}

// ---------------- host launcher ----------------
extern "C" void kernel_launch(void* const* d_in, const int* in_sizes, int n_in,
                              void* d_out, int out_size, void* d_ws, size_t ws_size,
                              hipStream_t stream) {
  const float* x  = (const float*)d_in[0];
  const float* fc = (const float*)d_in[1];
  const float* fs = (const float*)d_in[2];
  // d_in[3] = mask (causality implemented directly)
  const float* Wq = (const float*)d_in[4];
  const float* bq = (const float*)d_in[5];
  const float* Wk = (const float*)d_in[6];
  const float* bk = (const float*)d_in[7];
  const float* Wv = (const float*)d_in[8];
  const float* bv = (const float*)d_in[9];
  const float* Wo = (const float*)d_in[10];
  const float* bo = (const float*)d_in[11];
  float* out = (float*)d_out;

  char* ws = (char*)d_ws;
  unsigned short* xb    = (unsigned short*)(ws + 0);          // 8 MB (reused as attn out)
  unsigned short* WqkvT = (unsigned short*)(ws + 8388608);    // 12 MB (reused as VT)
  unsigned short* WoT   = (unsigned short*)(ws + 20971520);   // 8 MB
  float*          bqkv  = (float*)(ws + 29360128);            // 12 KB
  unsigned short* qkv   = (unsigned short*)(ws + 29372416);   // 12 MB
  unsigned short* VT    = WqkvT;                              // alias (after gemm1)
  unsigned short* attn  = xb;                                 // alias (after gemm1)

  prep_kernel<<<14348, 256, 0, stream>>>(x, bq, bk, bv, Wq, Wk, Wv, Wo,
                                         xb, WqkvT, WoT, bqkv);
  gemm_bt_kernel<3, 1><<<dim3(16, 32), 512, 0, stream>>>(xb, WqkvT, bqkv, qkv, 2048, 3072, 2048);
  rope_vt_kernel<<<11264, 256, 0, stream>>>(qkv, fc, fs, VT);
  attn_kernel<<<512, 512, 0, stream>>>(qkv, VT, attn);
  gemm_bt_kernel<2, 0><<<dim3(16, 32), 512, 0, stream>>>(attn, WoT, bo, out, 2048, 2048, 2048);
}